// Round 8
// baseline (266.494 us; speedup 1.0000x reference)
//
#include <hip/hip_runtime.h>
#include <hip/hip_fp16.h>
#include <math.h>

#define DIN 64
#define RECH 128   // halfs per record (256B stride): z[0..64), inv_s[64..80), el[80..84), er[84..88) (el/er pre-scaled by log2e)
#define LOG2E 1.44269504f
#define DEFER_THR 11.5415603f   // 8 * log2(e)
#define MAXDEG 4096             // safety cap against corrupt chains

__device__ __forceinline__ float fast_exp2(float x) {
    float r; asm("v_exp_f32 %0, %1" : "=v"(r) : "v"(x)); return r;
}
__device__ __forceinline__ int rfl(int x) { return __builtin_amdgcn_readfirstlane(x); }

// ---- DPP 16-lane row sum (butterfly: xor1, xor2, ror4, ror8) -> sum in all 16 lanes
template<int CTRL>
__device__ __forceinline__ float dppmov(float x) {
    union { float f; int i; } u, r;
    u.f = x;
    r.i = __builtin_amdgcn_update_dpp(0, u.i, CTRL, 0xF, 0xF, true);
    return r.f;
}
__device__ __forceinline__ float rowsum16(float x) {
    x += dppmov<0xB1>(x);    // quad_perm xor1
    x += dppmov<0x4E>(x);    // quad_perm xor2
    x += dppmov<0x124>(x);   // row_ror:4
    x += dppmov<0x128>(x);   // row_ror:8
    return x;
}

// ---------------- K1: role-split — edge blocks build linked list; mm blocks do transform ----------------
__global__ __launch_bounds__(256, 1) void transform_and_link(
    const float* __restrict__ feat, const float* __restrict__ W,
    const float* __restrict__ attn_l, const float* __restrict__ attn_r,
    const int* __restrict__ src, const int* __restrict__ dst, int e_n,
    int* __restrict__ head, int2* __restrict__ link,
    __half* __restrict__ rec, int n, int edge_blocks)
{
    int bid = blockIdx.x;
    if (bid < edge_blocks) {
        // linked-list build: 1 edge per thread, 1 atomic, coalesced link write
        int e = bid * 256 + threadIdx.x;
        if (e < e_n) {
            int d = dst[e];
            int s = src[e];
            int old = atomicExch(&head[d], e);
            link[e] = make_int2(old, s);
        }
        return;
    }
    int mb = bid - edge_blocks;

    int lane = threadIdx.x & 63;
    int h = lane >> 4, f = lane & 15;

    // W row `lane` resident in 64 VGPRs
    float4 wv[16];
    const float4* Wr = (const float4*)(W + (size_t)lane * 64);
#pragma unroll
    for (int i = 0; i < 16; i++) wv[i] = Wr[i];

    float al = attn_l[lane];
    float ar = attn_r[lane];

    int base = mb * 16 + (threadIdx.x >> 6) * 4;
#pragma unroll 1
    for (int k = 0; k < 4; k++) {
        int nidx = base + k;
        if (nidx >= n) break;
        int nu = rfl(nidx);
        const float4* frow = (const float4*)(feat + (size_t)nu * 64);

        float a0 = 0.f, a1 = 0.f, a2 = 0.f, a3 = 0.f;
#pragma unroll
        for (int i = 0; i < 4; i++) {
            float4 f0 = frow[i * 4 + 0], f1 = frow[i * 4 + 1];
            float4 f2 = frow[i * 4 + 2], f3 = frow[i * 4 + 3];
            a0 += f0.x * wv[i*4+0].x + f0.y * wv[i*4+0].y + f0.z * wv[i*4+0].z + f0.w * wv[i*4+0].w;
            a1 += f1.x * wv[i*4+1].x + f1.y * wv[i*4+1].y + f1.z * wv[i*4+1].z + f1.w * wv[i*4+1].w;
            a2 += f2.x * wv[i*4+2].x + f2.y * wv[i*4+2].y + f2.z * wv[i*4+2].z + f2.w * wv[i*4+2].w;
            a3 += f3.x * wv[i*4+3].x + f3.y * wv[i*4+3].y + f3.z * wv[i*4+3].z + f3.w * wv[i*4+3].w;
        }
        float zv = (a0 + a1) + (a2 + a3);

        float elv = rowsum16(zv * al) * LOG2E;
        float erv = rowsum16(zv * ar) * LOG2E;

        float sq = zv * zv;
        sq += __shfl_xor(sq, 16);
        sq += __shfl_xor(sq, 32);
        float isv = 1.0f / fmaxf(sq, 1e-3f);

        __half* r = rec + (size_t)nu * RECH;
        r[lane] = __float2half_rn(zv);
        if (h == 0) r[64 + f] = __float2half_rn(isv);
        if (f == 0) {
            r[80 + h] = __float2half_rn(elv);
            r[84 + h] = __float2half_rn(erv);
        }
    }
}

// ---------------- K2: chain-walk fused scores + deferred-max online softmax + aggregate ----------------
// One wave per dst node; 2-deep pipeline: while computing edge i, edge i+1's record
// loads and edge i+2's link load are in flight.
__global__ __launch_bounds__(256) void node_fused(
    const __half* __restrict__ rec,
    const int* __restrict__ head, const int2* __restrict__ link,
    float* __restrict__ out, int n)
{
    int lane = threadIdx.x & 63;
    int h = lane >> 4, f = lane & 15;
    int v = blockIdx.x * 4 + (threadIdx.x >> 6);
    if (v >= n) return;
    v = rfl(v);

    int ecur = rfl(head[v]);

    const __half* rv = rec + (size_t)v * RECH;
    float zv  = __half2float(rv[lane]);
    float isv = __half2float(rv[64 + f]);
    float erv = __half2float(rv[84 + h]);

    if (ecur < 0) { out[(size_t)v * 64 + lane] = 0.f; return; }

    // stage 0: link of current edge
    int2 t0 = link[ecur];
    int unow = rfl(t0.y);
    int enext = rfl(t0.x);

    // current record
    const __half* rc = rec + (size_t)unow * RECH;
    float za = __half2float(rc[lane]);
    float ia = __half2float(rc[64 + f]);
    float ea = __half2float(rc[80 + h]);

    // link of next edge
    int2 lnx = make_int2(-1, 0);
    if (enext >= 0) {
        int2 t1 = link[enext];
        lnx.x = rfl(t1.x);
        lnx.y = rfl(t1.y);
    }

    float m = -INFINITY, denom = 0.f, acc = 0.f;
    int guard = 0;

    while (true) {
        // issue next record loads + next-next link load
        float zb = 0.f, ib = 0.f, eb = 0.f;
        int e2 = -1;
        int2 ln2 = make_int2(-1, 0);
        if (enext >= 0) {
            const __half* rn = rec + (size_t)lnx.y * RECH;
            zb = __half2float(rn[lane]);
            ib = __half2float(rn[64 + f]);
            eb = __half2float(rn[80 + h]);
            e2 = lnx.x;
            if (e2 >= 0) {
                int2 t2 = link[e2];
                ln2.x = rfl(t2.x);
                ln2.y = rfl(t2.y);
            }
        }

        // compute on current (za/ia/ea)
        float edp = rowsum16(za * zv);
        float ffp = rowsum16(ia * isv);
        float s = fmaxf(edp * ffp, 0.f) * (ea + erv);

        if (s > m + DEFER_THR) {   // deferred-max rescale (first iter: exp2(-inf)=0 zeroes state)
            float c = fast_exp2(m - s);
            denom *= c; acc *= c; m = s;
        }
        float p = fast_exp2(s - m);
        denom += p;
        acc = fmaf(p, za, acc);

        if (enext < 0 || ++guard >= MAXDEG) break;
        za = zb; ia = ib; ea = eb;
        enext = e2; lnx = ln2;
    }
    out[(size_t)v * 64 + lane] = acc / denom;
}

extern "C" void kernel_launch(void* const* d_in, const int* in_sizes, int n_in,
                              void* d_out, int out_size, void* d_ws, size_t ws_size,
                              hipStream_t stream)
{
    const float* feat   = (const float*)d_in[0];
    const int*   src    = (const int*)d_in[1];
    const int*   dst    = (const int*)d_in[2];
    const float* W      = (const float*)d_in[3];
    const float* attn_l = (const float*)d_in[4];
    const float* attn_r = (const float*)d_in[5];
    float* out = (float*)d_out;

    const int n   = in_sizes[0] / DIN;   // 100000
    const int e_n = in_sizes[1];         // 1600000

    // workspace layout
    __half* rec  = (__half*)d_ws;                        // n*128 halfs (256B records) = 25.6 MB
    int*    head = (int*)(rec + (size_t)n * RECH);       // n ints (memset 0xFF -> -1)
    int2*   link = (int2*)(head + n);                    // e_n int2 {next, src} = 12.8 MB

    int edge_blocks = (e_n + 255) / 256;   // 6250
    int mm_blocks   = (n + 15) / 16;       // 6250

    hipMemsetAsync(head, 0xFF, (size_t)n * sizeof(int), stream);  // head = -1

    hipLaunchKernelGGL(transform_and_link, dim3(edge_blocks + mm_blocks), dim3(256), 0, stream,
                       feat, W, attn_l, attn_r, src, dst, e_n, head, link, rec, n, edge_blocks);

    hipLaunchKernelGGL(node_fused, dim3((n + 3) / 4), dim3(256), 0, stream,
                       rec, head, link, out, n);
}